// Round 1
// baseline (1215.930 us; speedup 1.0000x reference)
//
#include <hip/hip_runtime.h>
#include <hip/hip_bf16.h>

#define L_DIM  1024
#define N_DIM  64
#define IN_DIM 1024
#define OUT_DIM 1024

#define BM 128          // l-chunk per iteration (scan depth per chunk)
#define BN 128          // o-tile per block
#define BK 64           // K step
#define LDK 72          // BK + 8 pad (ushorts) -> row stride 144B, 2-way-free LDS banks
#define LDC 136         // BM + 8 pad (ushorts) -> 272B stride, b128-aligned, conflict-min

typedef __attribute__((ext_vector_type(8))) short  short8;   // 8 x bf16 (4 VGPRs) MFMA frag
typedef __attribute__((ext_vector_type(4))) float  f32x4;    // MFMA accumulator

// As/Bs (GEMM staging) and Ct (scan buffer) are live at disjoint times -> union.
union Smem {
  struct {
    unsigned short As[BM][LDK];   // spk tile, bf16, [l][k]
    unsigned short Bs[BN][LDK];   // W tile,   bf16, [o][k]
  } ab;
  unsigned short Ct[BN][LDC];     // cur tile, bf16, TRANSPOSED [o][l] for scan
};

static __device__ __forceinline__ unsigned short f2b(float f) {
  __hip_bfloat16 h = __float2bfloat16(f);   // RNE
  return __builtin_bit_cast(unsigned short, h);
}

__global__ __launch_bounds__(256, 2)
void lif_fused_kernel(const float* __restrict__ spk, const float* __restrict__ mem_in,
                      const float* __restrict__ W, const float* __restrict__ bias,
                      const float* __restrict__ beta, float* __restrict__ out) {
  __shared__ Smem sm;
  const int tid  = threadIdx.x;
  const int n    = blockIdx.x;           // batch; grid.x=64 so XCD = n%8 -> spk L2 locality
  const int ob   = blockIdx.y * BN;      // output-feature tile base
  const int wave = tid >> 6;
  const int lane = tid & 63;
  const int quad = lane >> 4;
  const int l15  = lane & 15;
  const int arow = (wave >> 1) * 64;     // wave's row (l) base within 128x128 tile
  const int bcol = (wave & 1) * 64;      // wave's col (o) base

  // persistent scan state: thread t (<128) owns output column ob+t
  float mem = 0.f, bo = 0.f, bt = 0.f;
  if (tid < BN) {
    const int og = ob + tid;
    mem = mem_in[n * OUT_DIM + og];
    bo  = bias[og];
    bt  = beta[og];
  }

  const f32x4 vzero = {0.f, 0.f, 0.f, 0.f};

  for (int ch = 0; ch < L_DIM / BM; ++ch) {
    f32x4 acc[4][4];
#pragma unroll
    for (int m = 0; m < 4; ++m)
#pragma unroll
      for (int t = 0; t < 4; ++t)
        acc[m][t] = vzero;

    for (int ks = 0; ks < IN_DIM / BK; ++ks) {
      const int k0 = ks * BK;
      __syncthreads();   // prev iter's frag reads / prev chunk's Ct scan reads done
      // --- stage A: spk[ch*BM..+128, n, k0..+64) fp32 -> bf16 LDS (128 rows x 16 float4)
#pragma unroll
      for (int j = 0; j < 8; ++j) {
        const int f = j * 256 + tid;
        const int r = f >> 4;
        const int c = (f & 15) << 2;
        const float4 v = *reinterpret_cast<const float4*>(
            spk + (size_t)((ch * BM + r) * N_DIM + n) * IN_DIM + k0 + c);
        ushort4 u;
        u.x = f2b(v.x); u.y = f2b(v.y); u.z = f2b(v.z); u.w = f2b(v.w);
        *reinterpret_cast<ushort4*>(&sm.ab.As[r][c]) = u;
      }
      // --- stage B: W[ob..+128, k0..+64)
#pragma unroll
      for (int j = 0; j < 8; ++j) {
        const int f = j * 256 + tid;
        const int r = f >> 4;
        const int c = (f & 15) << 2;
        const float4 v = *reinterpret_cast<const float4*>(
            W + (size_t)(ob + r) * IN_DIM + k0 + c);
        ushort4 u;
        u.x = f2b(v.x); u.y = f2b(v.y); u.z = f2b(v.z); u.w = f2b(v.w);
        *reinterpret_cast<ushort4*>(&sm.ab.Bs[r][c]) = u;
      }
      __syncthreads();
      // --- compute: 2 kk passes x 16 MFMA; frag = [idx=lane&15][k=quad*8+j] (contig 16B)
#pragma unroll
      for (int kk = 0; kk < BK; kk += 32) {
        short8 av[4], bv[4];
#pragma unroll
        for (int m = 0; m < 4; ++m)
          av[m] = *reinterpret_cast<const short8*>(&sm.ab.As[arow + m * 16 + l15][kk + quad * 8]);
#pragma unroll
        for (int t = 0; t < 4; ++t)
          bv[t] = *reinterpret_cast<const short8*>(&sm.ab.Bs[bcol + t * 16 + l15][kk + quad * 8]);
#pragma unroll
        for (int m = 0; m < 4; ++m)
#pragma unroll
          for (int t = 0; t < 4; ++t)
            acc[m][t] = __builtin_amdgcn_mfma_f32_16x16x32_bf16(av[m], bv[t], acc[m][t], 0, 0, 0);
      }
    }
    __syncthreads();   // all frag reads done before Ct overwrites As/Bs (union!)
    // --- dump acc -> Ct[o][l] as bf16; D layout: row = quad*4+reg, col = lane&15
#pragma unroll
    for (int m = 0; m < 4; ++m) {
      const int row = arow + m * 16 + quad * 4;
#pragma unroll
      for (int t = 0; t < 4; ++t) {
        const int col = bcol + t * 16 + l15;
        ushort4 u;
        u.x = f2b(acc[m][t][0]);
        u.y = f2b(acc[m][t][1]);
        u.z = f2b(acc[m][t][2]);
        u.w = f2b(acc[m][t][3]);
        *reinterpret_cast<ushort4*>(&sm.Ct[col][row]) = u;   // 4 consecutive l -> b64
      }
    }
    __syncthreads();
    // --- sequential scan along l (threads 0..127, one per o column), coalesced stores
    if (tid < BN) {
      const int og = ob + tid;
#pragma unroll
      for (int r8 = 0; r8 < BM / 8; ++r8) {
        const short8 v = *reinterpret_cast<const short8*>(&sm.Ct[tid][r8 * 8]);
#pragma unroll
        for (int j = 0; j < 8; ++j) {
          const float x = __builtin_bit_cast(float,
              (unsigned)((unsigned short)v[j]) << 16);
          mem = bt * mem + (x + bo);
          out[(size_t)((ch * BM + r8 * 8 + j) * N_DIM + n) * OUT_DIM + og] = mem;
        }
      }
    }
    // next chunk's first __syncthreads() protects Ct before As/Bs restaging
  }
  // final_mem output (N, OUT) appended after out_seq
  if (tid < BN) {
    out[(size_t)L_DIM * N_DIM * OUT_DIM + n * OUT_DIM + ob + tid] = mem;
  }
}

extern "C" void kernel_launch(void* const* d_in, const int* in_sizes, int n_in,
                              void* d_out, int out_size, void* d_ws, size_t ws_size,
                              hipStream_t stream) {
  const float* spk  = (const float*)d_in[0];
  const float* mem  = (const float*)d_in[1];
  const float* W    = (const float*)d_in[2];
  const float* bias = (const float*)d_in[3];
  const float* beta = (const float*)d_in[4];
  float* out = (float*)d_out;
  dim3 grid(N_DIM, OUT_DIM / BN);   // (64, 8): same-n blocks -> same XCD (id%8 == n%8)
  lif_fused_kernel<<<grid, dim3(256, 1, 1), 0, stream>>>(spk, mem, W, bias, beta, out);
}

// Round 2
// 991.857 us; speedup vs baseline: 1.2259x; 1.2259x over previous
//
#include <hip/hip_runtime.h>
#include <hip/hip_bf16.h>

#define L_DIM  1024
#define N_DIM  64
#define IN_DIM 1024
#define OUT_DIM 1024

#define BM 128          // l rows per GEMM block
#define BN 128          // o cols per GEMM block
#define BK 64           // K step
#define LDK 72          // BK + 8 pad (ushorts) -> 144B row stride

typedef __attribute__((ext_vector_type(8))) short  short8;   // 8 x bf16 MFMA frag
typedef __attribute__((ext_vector_type(4))) float  f32x4;    // MFMA accumulator

static __device__ __forceinline__ unsigned short f2b(float f) {
  __hip_bfloat16 h = __float2bfloat16(f);   // RNE
  return __builtin_bit_cast(unsigned short, h);
}

// ---------------- Pass 1: cur[l,n,o] = spk[l,n,:] @ W[o,:]^T + b[o]  (fp32 into out) ----
// grid (n=64, ot=8, lch=8) -> 4096 blocks; id%8 == n%8 so blocks sharing spk[:,n,:]
// land on one XCD (L2 locality for the A-tile re-reads across ot).
__global__ __launch_bounds__(256, 4)
void gemm_kernel(const float* __restrict__ spk, const float* __restrict__ W,
                 const float* __restrict__ bias, float* __restrict__ out) {
  __shared__ unsigned short As[BM][LDK];
  __shared__ unsigned short Bs[BN][LDK];
  const int tid  = threadIdx.x;
  const int n    = blockIdx.x;
  const int ob   = blockIdx.y * BN;
  const int lb   = blockIdx.z * BM;
  const int wave = tid >> 6;
  const int lane = tid & 63;
  const int quad = lane >> 4;
  const int l15  = lane & 15;
  const int arow = (wave >> 1) * 64;     // wave row (l) base in 128x128 tile
  const int bcol = (wave & 1) * 64;      // wave col (o) base

  // init acc with bias: C/D col = bcol + t*16 + (lane&15), same for all 4 regs & all m
  f32x4 acc[4][4];
#pragma unroll
  for (int t = 0; t < 4; ++t) {
    const float bv = bias[ob + bcol + t * 16 + l15];
    const f32x4 binit = {bv, bv, bv, bv};
#pragma unroll
    for (int m = 0; m < 4; ++m) acc[m][t] = binit;
  }

  for (int ks = 0; ks < IN_DIM / BK; ++ks) {
    const int k0 = ks * BK;
    __syncthreads();
    // stage A: spk rows l = lb..lb+127, cols k0..k0+63, fp32 -> bf16
#pragma unroll
    for (int j = 0; j < 8; ++j) {
      const int f = j * 256 + tid;
      const int r = f >> 4;
      const int c = (f & 15) << 2;
      const float4 v = *reinterpret_cast<const float4*>(
          spk + (size_t)((lb + r) * N_DIM + n) * IN_DIM + k0 + c);
      ushort4 u;
      u.x = f2b(v.x); u.y = f2b(v.y); u.z = f2b(v.z); u.w = f2b(v.w);
      *reinterpret_cast<ushort4*>(&As[r][c]) = u;
    }
    // stage B: W rows ob..ob+127
#pragma unroll
    for (int j = 0; j < 8; ++j) {
      const int f = j * 256 + tid;
      const int r = f >> 4;
      const int c = (f & 15) << 2;
      const float4 v = *reinterpret_cast<const float4*>(
          W + (size_t)(ob + r) * IN_DIM + k0 + c);
      ushort4 u;
      u.x = f2b(v.x); u.y = f2b(v.y); u.z = f2b(v.z); u.w = f2b(v.w);
      *reinterpret_cast<ushort4*>(&Bs[r][c]) = u;
    }
    __syncthreads();
#pragma unroll
    for (int kk = 0; kk < BK; kk += 32) {
      short8 av[4], bv[4];
#pragma unroll
      for (int m = 0; m < 4; ++m)
        av[m] = *reinterpret_cast<const short8*>(&As[arow + m * 16 + l15][kk + quad * 8]);
#pragma unroll
      for (int t = 0; t < 4; ++t)
        bv[t] = *reinterpret_cast<const short8*>(&Bs[bcol + t * 16 + l15][kk + quad * 8]);
#pragma unroll
      for (int m = 0; m < 4; ++m)
#pragma unroll
        for (int t = 0; t < 4; ++t)
          acc[m][t] = __builtin_amdgcn_mfma_f32_16x16x32_bf16(av[m], bv[t], acc[m][t], 0, 0, 0);
    }
  }
  // epilogue: direct fp32 stores. Per (m,t,reg): 4 quads hit 4 rows, 16 lanes = 64B seg;
  // t=0..3 tile 256B per row -> L2 merges.
#pragma unroll
  for (int m = 0; m < 4; ++m) {
#pragma unroll
    for (int t = 0; t < 4; ++t) {
      const int col = ob + bcol + t * 16 + l15;
#pragma unroll
      for (int j = 0; j < 4; ++j) {
        const int row = lb + arow + m * 16 + quad * 4 + j;
        out[(size_t)(row * N_DIM + n) * OUT_DIM + col] = acc[m][t][j];
      }
    }
  }
}

// ---------------- Pass 2: in-place diagonal scan along l ------------------------------
// mem = beta*mem + cur; one thread per (n,o) column; 16-deep load prefetch so the
// next chunk's loads are in flight during the FMA+store phase.
#define U 16
__global__ __launch_bounds__(256)
void scan_kernel(const float* __restrict__ mem_in, const float* __restrict__ beta,
                 float* __restrict__ out) {
  const int n = blockIdx.x;
  const int o = blockIdx.y * 256 + threadIdx.x;
  float mem = mem_in[n * OUT_DIM + o];
  const float bt = beta[o];
  const size_t base = (size_t)n * OUT_DIM + o;
  const size_t lstride = (size_t)N_DIM * OUT_DIM;

  float buf[U];
#pragma unroll
  for (int j = 0; j < U; ++j) buf[j] = out[base + (size_t)j * lstride];

  for (int c = 1; c < L_DIM / U; ++c) {
    float nb[U];
#pragma unroll
    for (int j = 0; j < U; ++j) nb[j] = out[base + (size_t)(c * U + j) * lstride];
#pragma unroll
    for (int j = 0; j < U; ++j) {
      mem = bt * mem + buf[j];
      out[base + (size_t)((c - 1) * U + j) * lstride] = mem;
      buf[j] = nb[j];
    }
  }
#pragma unroll
  for (int j = 0; j < U; ++j) {
    mem = bt * mem + buf[j];
    out[base + (size_t)((L_DIM - U) + j) * lstride] = mem;
  }
  // final_mem appended after out_seq
  out[(size_t)L_DIM * N_DIM * OUT_DIM + n * OUT_DIM + o] = mem;
}

extern "C" void kernel_launch(void* const* d_in, const int* in_sizes, int n_in,
                              void* d_out, int out_size, void* d_ws, size_t ws_size,
                              hipStream_t stream) {
  const float* spk  = (const float*)d_in[0];
  const float* mem  = (const float*)d_in[1];
  const float* W    = (const float*)d_in[2];
  const float* bias = (const float*)d_in[3];
  const float* beta = (const float*)d_in[4];
  float* out = (float*)d_out;

  dim3 g1(N_DIM, OUT_DIM / BN, L_DIM / BM);   // (64, 8, 8) = 4096 blocks
  gemm_kernel<<<g1, dim3(256, 1, 1), 0, stream>>>(spk, W, bias, out);

  dim3 g2(N_DIM, OUT_DIM / 256);              // (64, 4) = 256 blocks
  scan_kernel<<<g2, dim3(256, 1, 1), 0, stream>>>(mem, beta, out);
}